// Round 1
// baseline (1567.426 us; speedup 1.0000x reference)
//
#include <hip/hip_runtime.h>
#include <cstdint>
#include <cstddef>

// Problem constants (fixed by setup_inputs)
#define BB    2
#define LL    2048
#define DMODEL 1024
#define INNER 2048
#define NST   16
#define KCONV 4
#define DRANK 64
#define MROWS (BB*LL)   // 4096

// ---------------------------------------------------------------------------
// C[M,N] = A[M,K] @ B[N,K]^T   (both row-major, K contiguous — "NT" gemm)
// MODE 0: plain store.  MODE 1: softplus(c + bias[col])
// 64x64 tile, 256 threads, 4x4 per thread, K-tile 16.
// ---------------------------------------------------------------------------
template<int MODE>
__global__ __launch_bounds__(256)
void gemm_nt(const float* __restrict__ A, int lda,
             const float* __restrict__ Bm, int ldb,
             float* __restrict__ C, int ldc,
             int M, int N, int K,
             const float* __restrict__ bias)
{
    __shared__ float As[16][64];   // [k][m]
    __shared__ float Bs[16][64];   // [k][n]
    const int m0 = blockIdx.x * 64;
    const int n0 = blockIdx.y * 64;
    const int tid = threadIdx.x;
    const int tm = tid >> 4;          // 0..15
    const int tn = tid & 15;          // 0..15
    const int lrow = tid >> 2;        // 0..63
    const int lk   = (tid & 3) << 2;  // 0,4,8,12

    float acc[4][4] = {{0.f}};

    for (int k0 = 0; k0 < K; k0 += 16) {
        // stage A tile (M is always a multiple of 64 here -> no m guard)
        float4 a4 = *(const float4*)(A + (size_t)(m0 + lrow) * lda + (k0 + lk));
        // stage B tile with N guard (N=96 case)
        float4 b4 = make_float4(0.f, 0.f, 0.f, 0.f);
        if (n0 + lrow < N)
            b4 = *(const float4*)(Bm + (size_t)(n0 + lrow) * ldb + (k0 + lk));
        As[lk+0][lrow] = a4.x; As[lk+1][lrow] = a4.y;
        As[lk+2][lrow] = a4.z; As[lk+3][lrow] = a4.w;
        Bs[lk+0][lrow] = b4.x; Bs[lk+1][lrow] = b4.y;
        Bs[lk+2][lrow] = b4.z; Bs[lk+3][lrow] = b4.w;
        __syncthreads();
        #pragma unroll
        for (int kk = 0; kk < 16; ++kk) {
            float4 av = *(const float4*)&As[kk][tm << 2];
            float4 bv = *(const float4*)&Bs[kk][tn << 2];
            float am[4] = {av.x, av.y, av.z, av.w};
            float bn[4] = {bv.x, bv.y, bv.z, bv.w};
            #pragma unroll
            for (int i = 0; i < 4; ++i)
                #pragma unroll
                for (int j = 0; j < 4; ++j)
                    acc[i][j] = fmaf(am[i], bn[j], acc[i][j]);
        }
        __syncthreads();
    }

    #pragma unroll
    for (int i = 0; i < 4; ++i) {
        const int row = m0 + (tm << 2) + i;
        #pragma unroll
        for (int j = 0; j < 4; ++j) {
            const int col = n0 + (tn << 2) + j;
            if (col < N) {
                float v = acc[i][j];
                if (MODE == 1) {
                    v += bias[col];
                    v = (v > 20.f) ? v : log1pf(__expf(v));
                }
                C[(size_t)row * ldc + col] = v;
            }
        }
    }
}

// ---------------------------------------------------------------------------
// Depthwise causal conv (k=4) over the u half of xz, then SiLU.
// xz: [M, 2*INNER] (u = cols 0..INNER-1); u_act: [M, INNER]
// ---------------------------------------------------------------------------
__global__ __launch_bounds__(256)
void conv_silu(const float* __restrict__ xz,
               const float* __restrict__ conv_w,
               float* __restrict__ u_act)
{
    const int idx = blockIdx.x * 256 + threadIdx.x;   // 0 .. 2^23-1
    const int d  = idx & (INNER - 1);
    const int t  = (idx >> 11) & (LL - 1);
    const int bb = idx >> 22;
    float s = 0.f;
    #pragma unroll
    for (int j = 0; j < KCONV; ++j) {
        const int ts = t + j - (KCONV - 1);
        if (ts >= 0)
            s = fmaf(xz[((size_t)(bb * LL + ts)) * (2 * INNER) + d],
                     conv_w[d * KCONV + j], s);
    }
    const float sl = s / (1.f + __expf(-s));
    u_act[idx] = sl;
}

// ---------------------------------------------------------------------------
// Selective scan. One block = 16 channels x 16 states; 256 blocks total.
// Stages 64-timestep chunks of dt/u/gate/B/C into LDS, scans from LDS.
// Epilogue fused: yg = (y + u*D) * silu(gate)
// ---------------------------------------------------------------------------
__global__ __launch_bounds__(256)
void scan_kernel(const float* __restrict__ u_act,  // [M, INNER]
                 const float* __restrict__ dtb,    // [M, INNER]
                 const float* __restrict__ params, // [M, 96]; B at 64.., C at 80..
                 const float* __restrict__ xz,     // [M, 4096]; gate at col INNER+
                 const float* __restrict__ log_A,  // [INNER, NST]
                 const float* __restrict__ Dv,     // [INNER]
                 float* __restrict__ yg)           // [M, INNER]
{
    const int bb = blockIdx.x >> 7;          // 0..1
    const int d0 = (blockIdx.x & 127) << 4;  // channel base
    const int tid = threadIdx.x;
    const int nn = tid & 15;       // state index
    const int dl = tid >> 4;       // local channel 0..15
    const int d  = d0 + dl;

    const float Aval = -__expf(log_A[d * NST + nn]);  // A = -exp(log_A)
    const float Dd = Dv[d];
    float h = 0.f;

    __shared__ float dt_s[64][16];
    __shared__ float u_s[64][16];
    __shared__ float g_s[64][16];
    __shared__ float bc_s[64][32];

    const size_t rowbase = (size_t)bb * LL;

    for (int t0 = 0; t0 < LL; t0 += 64) {
        __syncthreads();
        for (int i = tid; i < 64 * 16; i += 256) {
            const int tt = i >> 4, dd = i & 15;
            const size_t r = rowbase + t0 + tt;
            dt_s[tt][dd] = dtb[r * INNER + d0 + dd];
            u_s[tt][dd]  = u_act[r * INNER + d0 + dd];
            g_s[tt][dd]  = xz[r * (2 * INNER) + INNER + d0 + dd];
        }
        for (int i = tid; i < 64 * 32; i += 256) {
            const int tt = i >> 5, cc = i & 31;
            bc_s[tt][cc] = params[(rowbase + t0 + tt) * 96 + 64 + cc];
        }
        __syncthreads();

        #pragma unroll 4
        for (int tt = 0; tt < 64; ++tt) {
            const float dtv = dt_s[tt][dl];
            const float uv  = u_s[tt][dl];
            const float Bv  = bc_s[tt][nn];
            const float Cv  = bc_s[tt][16 + nn];
            const float a = __expf(dtv * Aval);
            h = fmaf(a, h, dtv * uv * Bv);
            float p = h * Cv;
            p += __shfl_xor(p, 1, 16);
            p += __shfl_xor(p, 2, 16);
            p += __shfl_xor(p, 4, 16);
            p += __shfl_xor(p, 8, 16);
            if (nn == 0) {
                const float gv = g_s[tt][dl];
                const float sg = gv / (1.f + __expf(-gv));
                yg[(rowbase + t0 + tt) * INNER + d0 + dl] = (p + uv * Dd) * sg;
            }
        }
    }
}

// ---------------------------------------------------------------------------
extern "C" void kernel_launch(void* const* d_in, const int* in_sizes, int n_in,
                              void* d_out, int out_size, void* d_ws, size_t ws_size,
                              hipStream_t stream)
{
    const float* x     = (const float*)d_in[0];  // [2,2048,1024]
    const float* W_in  = (const float*)d_in[1];  // [4096,1024]
    const float* convw = (const float*)d_in[2];  // [2048,4]
    const float* W_ssm = (const float*)d_in[3];  // [96,2048]
    const float* W_dt  = (const float*)d_in[4];  // [2048,64]
    const float* b_dt  = (const float*)d_in[5];  // [2048]
    const float* log_A = (const float*)d_in[6];  // [2048,16]
    const float* Dv    = (const float*)d_in[7];  // [2048]
    const float* W_out = (const float*)d_in[8];  // [1024,2048]
    float* out = (float*)d_out;                  // [2,2048,1024] fp32

    float* ws = (float*)d_ws;
    float* xz     = ws;                                   // 4096*4096
    float* u_act  = xz     + (size_t)MROWS * 2 * INNER;   // 4096*2048
    float* dt_buf = u_act  + (size_t)MROWS * INNER;       // 4096*2048
    float* yg     = dt_buf + (size_t)MROWS * INNER;       // 4096*2048
    float* params = yg     + (size_t)MROWS * INNER;       // 4096*96

    // 1. xz = x @ W_in.T                     M=4096 N=4096 K=1024
    gemm_nt<0><<<dim3(64, 64), 256, 0, stream>>>(
        x, DMODEL, W_in, DMODEL, xz, 2 * INNER,
        MROWS, 2 * INNER, DMODEL, nullptr);

    // 2. u_act = silu(causal_conv(u))
    conv_silu<<<(MROWS * INNER) / 256, 256, 0, stream>>>(xz, convw, u_act);

    // 3. params = u_act @ W_ssm.T            M=4096 N=96 K=2048
    gemm_nt<0><<<dim3(64, 2), 256, 0, stream>>>(
        u_act, INNER, W_ssm, INNER, params, 96,
        MROWS, 96, INNER, nullptr);

    // 4. dt = softplus(d_low @ W_dt.T + b_dt)  M=4096 N=2048 K=64 (lda=96!)
    gemm_nt<1><<<dim3(64, 32), 256, 0, stream>>>(
        params, 96, W_dt, DRANK, dt_buf, INNER,
        MROWS, INNER, DRANK, b_dt);

    // 5. selective scan + fused (y + u*D) * silu(gate)
    scan_kernel<<<BB * (INNER / 16), 256, 0, stream>>>(
        u_act, dt_buf, params, xz, log_A, Dv, yg);

    // 6. out = yg @ W_out.T                  M=4096 N=1024 K=2048
    gemm_nt<0><<<dim3(64, 16), 256, 0, stream>>>(
        yg, INNER, W_out, INNER, out, DMODEL,
        MROWS, DMODEL, INNER, nullptr);
}

// Round 2
// 1110.189 us; speedup vs baseline: 1.4119x; 1.4119x over previous
//
#include <hip/hip_runtime.h>
#include <cstdint>
#include <cstddef>

// Problem constants (fixed by setup_inputs)
#define BB     2
#define LL     2048
#define DMODEL 1024
#define INNER  2048
#define NST    16
#define KCONV  4
#define DRANK  64
#define MROWS  (BB*LL)   // 4096
#define SCH    64        // time chunks
#define TCH    (LL/SCH)  // 32 timesteps per chunk

// ---------------------------------------------------------------------------
// C[M,N] = A[M,K] @ B[N,K]^T   (both row-major, K contiguous — "NT" gemm)
// MODE 0: plain store.  MODE 1: softplus(c + bias[col])
// 64x64 tile, 256 threads, 4x4 per thread, K-tile 16.
// ---------------------------------------------------------------------------
template<int MODE>
__global__ __launch_bounds__(256)
void gemm_nt(const float* __restrict__ A, int lda,
             const float* __restrict__ Bm, int ldb,
             float* __restrict__ C, int ldc,
             int M, int N, int K,
             const float* __restrict__ bias)
{
    __shared__ float As[16][64];   // [k][m]
    __shared__ float Bs[16][64];   // [k][n]
    const int m0 = blockIdx.x * 64;
    const int n0 = blockIdx.y * 64;
    const int tid = threadIdx.x;
    const int tm = tid >> 4;          // 0..15
    const int tn = tid & 15;          // 0..15
    const int lrow = tid >> 2;        // 0..63
    const int lk   = (tid & 3) << 2;  // 0,4,8,12

    float acc[4][4] = {{0.f}};

    for (int k0 = 0; k0 < K; k0 += 16) {
        float4 a4 = *(const float4*)(A + (size_t)(m0 + lrow) * lda + (k0 + lk));
        float4 b4 = make_float4(0.f, 0.f, 0.f, 0.f);
        if (n0 + lrow < N)
            b4 = *(const float4*)(Bm + (size_t)(n0 + lrow) * ldb + (k0 + lk));
        As[lk+0][lrow] = a4.x; As[lk+1][lrow] = a4.y;
        As[lk+2][lrow] = a4.z; As[lk+3][lrow] = a4.w;
        Bs[lk+0][lrow] = b4.x; Bs[lk+1][lrow] = b4.y;
        Bs[lk+2][lrow] = b4.z; Bs[lk+3][lrow] = b4.w;
        __syncthreads();
        #pragma unroll
        for (int kk = 0; kk < 16; ++kk) {
            float4 av = *(const float4*)&As[kk][tm << 2];
            float4 bv = *(const float4*)&Bs[kk][tn << 2];
            float am[4] = {av.x, av.y, av.z, av.w};
            float bn[4] = {bv.x, bv.y, bv.z, bv.w};
            #pragma unroll
            for (int i = 0; i < 4; ++i)
                #pragma unroll
                for (int j = 0; j < 4; ++j)
                    acc[i][j] = fmaf(am[i], bn[j], acc[i][j]);
        }
        __syncthreads();
    }

    #pragma unroll
    for (int i = 0; i < 4; ++i) {
        const int row = m0 + (tm << 2) + i;
        #pragma unroll
        for (int j = 0; j < 4; ++j) {
            const int col = n0 + (tn << 2) + j;
            if (col < N) {
                float v = acc[i][j];
                if (MODE == 1) {
                    v += bias[col];
                    v = (v > 20.f) ? v : log1pf(__expf(v));
                }
                C[(size_t)row * ldc + col] = v;
            }
        }
    }
}

// ---------------------------------------------------------------------------
// Depthwise causal conv (k=4) over the u half of xz, then SiLU.
// ---------------------------------------------------------------------------
__global__ __launch_bounds__(256)
void conv_silu(const float* __restrict__ xz,
               const float* __restrict__ conv_w,
               float* __restrict__ u_act)
{
    const int idx = blockIdx.x * 256 + threadIdx.x;
    const int d  = idx & (INNER - 1);
    const int t  = (idx >> 11) & (LL - 1);
    const int bb = idx >> 22;
    float s = 0.f;
    #pragma unroll
    for (int j = 0; j < KCONV; ++j) {
        const int ts = t + j - (KCONV - 1);
        if (ts >= 0)
            s = fmaf(xz[((size_t)(bb * LL + ts)) * (2 * INNER) + d],
                     conv_w[d * KCONV + j], s);
    }
    u_act[idx] = s / (1.f + __expf(-s));
}

// ---------------------------------------------------------------------------
// Scan pass 1: per-chunk summaries. One thread = one channel of one chunk,
// holds h[16] in registers. Outputs: H (chunk-local final state from h=0)
// and sum(dt) over the chunk (P_n = exp(A_n * sumdt)).
// Grid: BB * (INNER/256) * SCH = 1024 blocks.
// ---------------------------------------------------------------------------
__global__ __launch_bounds__(256)
void scan_pass1(const float* __restrict__ u_act,
                const float* __restrict__ dtb,
                const float* __restrict__ params,
                const float* __restrict__ log_A,
                float* __restrict__ Hout,
                float* __restrict__ sumdt_out)
{
    const int bid = blockIdx.x;
    const int c   = bid & (SCH - 1);
    const int cg  = (bid >> 6) & 7;
    const int b   = bid >> 9;
    const int tid = threadIdx.x;
    const int d   = cg * 256 + tid;
    const size_t rowbase = (size_t)b * LL + (size_t)c * TCH;

    float A[NST];
    #pragma unroll
    for (int n = 0; n < NST; n += 4) {
        float4 v = *(const float4*)(log_A + (size_t)d * NST + n);
        A[n+0] = -__expf(v.x); A[n+1] = -__expf(v.y);
        A[n+2] = -__expf(v.z); A[n+3] = -__expf(v.w);
    }

    __shared__ float Bs[TCH * NST];
    for (int i = tid; i < TCH * NST; i += 256) {
        const int t = i >> 4, j = i & 15;
        Bs[i] = params[(rowbase + t) * 96 + DRANK + j];
    }
    __syncthreads();

    float h[NST];
    #pragma unroll
    for (int n = 0; n < NST; ++n) h[n] = 0.f;
    float sdt = 0.f;

    #pragma unroll 4
    for (int t = 0; t < TCH; ++t) {
        const float dtv = dtb[(rowbase + t) * INNER + d];
        const float uv  = u_act[(rowbase + t) * INNER + d];
        const float du = dtv * uv;
        sdt += dtv;
        const float4* Bp = (const float4*)&Bs[t * NST];
        const float4 B0 = Bp[0], B1 = Bp[1], B2 = Bp[2], B3 = Bp[3];
        const float Bv[NST] = {B0.x,B0.y,B0.z,B0.w, B1.x,B1.y,B1.z,B1.w,
                               B2.x,B2.y,B2.z,B2.w, B3.x,B3.y,B3.z,B3.w};
        #pragma unroll
        for (int n = 0; n < NST; ++n)
            h[n] = fmaf(__expf(dtv * A[n]), h[n], du * Bv[n]);
    }

    const size_t o = ((size_t)(b * SCH + c) * INNER + d) * NST;
    #pragma unroll
    for (int n = 0; n < NST; n += 4)
        *(float4*)(Hout + o + n) = make_float4(h[n], h[n+1], h[n+2], h[n+3]);
    sumdt_out[(size_t)(b * SCH + c) * INNER + d] = sdt;
}

// ---------------------------------------------------------------------------
// Scan pass 2: serial combine over chunks. One thread = one (b,d,n).
// h_init[c] = H[c-1] + exp(A_n*sumdt[c-1]) * h_init[c-1],  h_init[0] = 0.
// ---------------------------------------------------------------------------
__global__ __launch_bounds__(256)
void scan_pass2(const float* __restrict__ Hbuf,
                const float* __restrict__ sumdt,
                const float* __restrict__ log_A,
                float* __restrict__ hinit)
{
    const int idx = blockIdx.x * 256 + threadIdx.x;  // 65536 = (b, d, n)
    const int n = idx & 15;
    const int d = (idx >> 4) & (INNER - 1);
    const int b = idx >> 15;
    const float An = -__expf(log_A[(size_t)d * NST + n]);
    float h = 0.f;
    for (int c = 0; c < SCH; ++c) {
        const size_t o = ((size_t)(b * SCH + c) * INNER + d) * NST + n;
        hinit[o] = h;
        const float P = __expf(An * sumdt[(size_t)(b * SCH + c) * INNER + d]);
        h = Hbuf[o] + P * h;
    }
}

// ---------------------------------------------------------------------------
// Scan pass 3: re-scan each chunk from h_init, fused epilogue:
// yg = (y + u*D) * silu(gate). Writes into the (dead) u-half of xz (ldy=4096).
// ---------------------------------------------------------------------------
__global__ __launch_bounds__(256)
void scan_pass3(const float* __restrict__ u_act,
                const float* __restrict__ dtb,
                const float* __restrict__ params,
                const float* __restrict__ xz,     // gate at col INNER+d
                const float* __restrict__ log_A,
                const float* __restrict__ Dv,
                const float* __restrict__ hinit,
                float* __restrict__ yg, int ldy)
{
    const int bid = blockIdx.x;
    const int c   = bid & (SCH - 1);
    const int cg  = (bid >> 6) & 7;
    const int b   = bid >> 9;
    const int tid = threadIdx.x;
    const int d   = cg * 256 + tid;
    const size_t rowbase = (size_t)b * LL + (size_t)c * TCH;

    float A[NST];
    #pragma unroll
    for (int n = 0; n < NST; n += 4) {
        float4 v = *(const float4*)(log_A + (size_t)d * NST + n);
        A[n+0] = -__expf(v.x); A[n+1] = -__expf(v.y);
        A[n+2] = -__expf(v.z); A[n+3] = -__expf(v.w);
    }
    const float Dd = Dv[d];

    __shared__ float BCs[TCH * 32];
    for (int i = tid; i < TCH * 32; i += 256) {
        const int t = i >> 5, j = i & 31;
        BCs[i] = params[(rowbase + t) * 96 + DRANK + j];
    }

    float h[NST];
    {
        const size_t o = ((size_t)(b * SCH + c) * INNER + d) * NST;
        #pragma unroll
        for (int n = 0; n < NST; n += 4) {
            float4 v = *(const float4*)(hinit + o + n);
            h[n] = v.x; h[n+1] = v.y; h[n+2] = v.z; h[n+3] = v.w;
        }
    }
    __syncthreads();

    #pragma unroll 2
    for (int t = 0; t < TCH; ++t) {
        const float dtv = dtb[(rowbase + t) * INNER + d];
        const float uv  = u_act[(rowbase + t) * INNER + d];
        const float gv  = xz[(rowbase + t) * (2 * INNER) + INNER + d];
        const float du = dtv * uv;
        const float4* Bp = (const float4*)&BCs[t * 32];
        const float4 B0 = Bp[0], B1 = Bp[1], B2 = Bp[2], B3 = Bp[3];
        const float4 C0 = Bp[4], C1 = Bp[5], C2 = Bp[6], C3 = Bp[7];
        const float Bv[NST] = {B0.x,B0.y,B0.z,B0.w, B1.x,B1.y,B1.z,B1.w,
                               B2.x,B2.y,B2.z,B2.w, B3.x,B3.y,B3.z,B3.w};
        const float Cv[NST] = {C0.x,C0.y,C0.z,C0.w, C1.x,C1.y,C1.z,C1.w,
                               C2.x,C2.y,C2.z,C2.w, C3.x,C3.y,C3.z,C3.w};
        #pragma unroll
        for (int n = 0; n < NST; ++n)
            h[n] = fmaf(__expf(dtv * A[n]), h[n], du * Bv[n]);
        // pairwise-tree dot over n
        float p[8];
        #pragma unroll
        for (int n = 0; n < 8; ++n)
            p[n] = fmaf(h[n], Cv[n], h[n+8] * Cv[n+8]);
        const float y = ((p[0]+p[1]) + (p[2]+p[3])) + ((p[4]+p[5]) + (p[6]+p[7]));
        const float sg = gv / (1.f + __expf(-gv));
        yg[(rowbase + t) * ldy + d] = (y + uv * Dd) * sg;
    }
}

// ---------------------------------------------------------------------------
extern "C" void kernel_launch(void* const* d_in, const int* in_sizes, int n_in,
                              void* d_out, int out_size, void* d_ws, size_t ws_size,
                              hipStream_t stream)
{
    const float* x     = (const float*)d_in[0];
    const float* W_in  = (const float*)d_in[1];
    const float* convw = (const float*)d_in[2];
    const float* W_ssm = (const float*)d_in[3];
    const float* W_dt  = (const float*)d_in[4];
    const float* b_dt  = (const float*)d_in[5];
    const float* log_A = (const float*)d_in[6];
    const float* Dv    = (const float*)d_in[7];
    const float* W_out = (const float*)d_in[8];
    float* out = (float*)d_out;

    float* ws = (float*)d_ws;
    float* xz     = ws;                                   // 4096*4096
    float* u_act  = xz     + (size_t)MROWS * 2 * INNER;   // 4096*2048
    float* dt_buf = u_act  + (size_t)MROWS * INNER;       // 4096*2048
    float* params = dt_buf + (size_t)MROWS * INNER;       // 4096*96
    float* Hbuf   = params + (size_t)MROWS * 96;          // 2*64*2048*16
    float* hinit  = Hbuf   + (size_t)BB * SCH * INNER * NST;
    float* sumdt  = hinit  + (size_t)BB * SCH * INNER * NST;  // 2*64*2048

    // 1. xz = x @ W_in.T                     M=4096 N=4096 K=1024
    gemm_nt<0><<<dim3(64, 64), 256, 0, stream>>>(
        x, DMODEL, W_in, DMODEL, xz, 2 * INNER,
        MROWS, 2 * INNER, DMODEL, nullptr);

    // 2. u_act = silu(causal_conv(u))
    conv_silu<<<(MROWS * INNER) / 256, 256, 0, stream>>>(xz, convw, u_act);

    // 3. params = u_act @ W_ssm.T            M=4096 N=96 K=2048
    gemm_nt<0><<<dim3(64, 2), 256, 0, stream>>>(
        u_act, INNER, W_ssm, INNER, params, 96,
        MROWS, 96, INNER, nullptr);

    // 4. dt = softplus(d_low @ W_dt.T + b_dt)  M=4096 N=2048 K=64 (lda=96)
    gemm_nt<1><<<dim3(64, 32), 256, 0, stream>>>(
        params, 96, W_dt, DRANK, dt_buf, INNER,
        MROWS, INNER, DRANK, b_dt);

    // 5. chunked selective scan (3 passes)
    scan_pass1<<<BB * (INNER / 256) * SCH, 256, 0, stream>>>(
        u_act, dt_buf, params, log_A, Hbuf, sumdt);
    scan_pass2<<<BB * INNER * NST / 256, 256, 0, stream>>>(
        Hbuf, sumdt, log_A, hinit);
    // yg written into the (now dead) u-half of xz, ld = 4096
    scan_pass3<<<BB * (INNER / 256) * SCH, 256, 0, stream>>>(
        u_act, dt_buf, params, xz, log_A, Dv, hinit, xz, 2 * INNER);

    // 6. out = yg @ W_out.T                  M=4096 N=1024 K=2048
    gemm_nt<0><<<dim3(64, 16), 256, 0, stream>>>(
        xz, 2 * INNER, W_out, INNER, out, DMODEL,
        MROWS, DMODEL, INNER, nullptr);
}

// Round 3
// 668.949 us; speedup vs baseline: 2.3431x; 1.6596x over previous
//
#include <hip/hip_runtime.h>
#include <cstdint>
#include <cstddef>

// Problem constants (fixed by setup_inputs)
#define BB     2
#define LL     2048
#define DMODEL 1024
#define INNER  2048
#define NST    16
#define KCONV  4
#define DRANK  64
#define MROWS  (BB*LL)   // 4096
#define SCH    64        // time chunks
#define TCH    (LL/SCH)  // 32 timesteps per chunk

typedef __attribute__((ext_vector_type(8))) short short8;   // 8 bf16 = 4 VGPRs
typedef __attribute__((ext_vector_type(4))) float floatx4;

__device__ __forceinline__ unsigned short f2bf(float f) {   // RNE fp32->bf16
    unsigned int u = __float_as_uint(f);
    return (unsigned short)((u + 0x7FFFu + ((u >> 16) & 1u)) >> 16);
}
__device__ __forceinline__ float bf2f(unsigned short h) {
    return __uint_as_float(((unsigned int)h) << 16);
}

// async global->LDS, 16B per lane, dest = wave-uniform base + lane*16
#define GLL(gp, lp) __builtin_amdgcn_global_load_lds( \
    (const __attribute__((address_space(1))) unsigned int*)(gp), \
    (__attribute__((address_space(3))) unsigned int*)(lp), 16, 0, 0)

// ---------------------------------------------------------------------------
// Split fp32 -> (hi, lo) bf16 planes. hi = bf16(v), lo = bf16(v - hi).
// Input rows of `cols4*4` elements with leading dim `ld`; output packed.
// ---------------------------------------------------------------------------
__global__ __launch_bounds__(256)
void split_bf16(const float* __restrict__ in, int ld, int cols4,
                unsigned short* __restrict__ hi, unsigned short* __restrict__ lo,
                int total4)
{
    const int idx = blockIdx.x * 256 + threadIdx.x;
    if (idx >= total4) return;
    const int row = idx / cols4;
    const int cq  = idx - row * cols4;
    const float4 v = *(const float4*)(in + (size_t)row * ld + (size_t)cq * 4);
    ushort4 h, l;
    h.x = f2bf(v.x); l.x = f2bf(v.x - bf2f(h.x));
    h.y = f2bf(v.y); l.y = f2bf(v.y - bf2f(h.y));
    h.z = f2bf(v.z); l.z = f2bf(v.z - bf2f(h.z));
    h.w = f2bf(v.w); l.w = f2bf(v.w - bf2f(h.w));
    const size_t o = ((size_t)row * cols4 + cq) * 4;
    *(ushort4*)(hi + o) = h;
    *(ushort4*)(lo + o) = l;
}

// ---------------------------------------------------------------------------
// bf16x3 MFMA NT-GEMM: C[M,N] = (Ah+Al)[M,K] @ (Bh+Bl)[N,K]^T (lo*lo dropped)
// 128x128 tile, 4 waves, each 4x4 tiles of mfma_f32_16x16x32_bf16, BK=32.
// LDS planes stored k-group-major: [kq 0..3][row 0..127][8 bf16] so that
// global_load_lds (lane-contiguous) and frag ds_read_b128 both line up.
// Requires M,N % 128 == 0 and K % 32 == 0.
// ---------------------------------------------------------------------------
__global__ __launch_bounds__(256)
void gemm_bf16x3(const unsigned short* __restrict__ Ah,
                 const unsigned short* __restrict__ Al, int lda,
                 const unsigned short* __restrict__ Bh,
                 const unsigned short* __restrict__ Bl, int ldb,
                 float* __restrict__ C, int ldc, int K)
{
    __shared__ __align__(16) unsigned short sAh[4 * 128 * 8];
    __shared__ __align__(16) unsigned short sAl[4 * 128 * 8];
    __shared__ __align__(16) unsigned short sBh[4 * 128 * 8];
    __shared__ __align__(16) unsigned short sBl[4 * 128 * 8];

    const int tid  = threadIdx.x;
    const int w    = tid >> 6;        // wave 0..3
    const int lane = tid & 63;
    const int ln15 = lane & 15;
    const int q    = lane >> 4;       // k-quad 0..3
    const int wm   = w & 1, wn = w >> 1;
    const int m0 = blockIdx.x * 128, n0 = blockIdx.y * 128;

    floatx4 acc[4][4];
    #pragma unroll
    for (int i = 0; i < 4; ++i)
        #pragma unroll
        for (int j = 0; j < 4; ++j)
            acc[i][j] = (floatx4){0.f, 0.f, 0.f, 0.f};

    // per-lane global row offsets for staging (lane -> row, wave -> k-group)
    const size_t a0 = (size_t)(m0 + lane) * lda;
    const size_t a1 = (size_t)(m0 + 64 + lane) * lda;
    const size_t b0 = (size_t)(n0 + lane) * ldb;
    const size_t b1 = (size_t)(n0 + 64 + lane) * ldb;

    // wave-uniform LDS bases: wave w owns k-group w, both 64-row halves
    unsigned short* lah0 = &sAh[(w * 128 +  0) * 8];
    unsigned short* lah1 = &sAh[(w * 128 + 64) * 8];
    unsigned short* lal0 = &sAl[(w * 128 +  0) * 8];
    unsigned short* lal1 = &sAl[(w * 128 + 64) * 8];
    unsigned short* lbh0 = &sBh[(w * 128 +  0) * 8];
    unsigned short* lbh1 = &sBh[(w * 128 + 64) * 8];
    unsigned short* lbl0 = &sBl[(w * 128 +  0) * 8];
    unsigned short* lbl1 = &sBl[(w * 128 + 64) * 8];

    for (int k0 = 0; k0 < K; k0 += 32) {
        const int kg = k0 + w * 8;
        GLL(Ah + a0 + kg, lah0);
        GLL(Ah + a1 + kg, lah1);
        GLL(Al + a0 + kg, lal0);
        GLL(Al + a1 + kg, lal1);
        GLL(Bh + b0 + kg, lbh0);
        GLL(Bh + b1 + kg, lbh1);
        GLL(Bl + b0 + kg, lbl0);
        GLL(Bl + b1 + kg, lbl1);
        __syncthreads();

        short8 fah[4], fal[4], fbh[4], fbl[4];
        #pragma unroll
        for (int i = 0; i < 4; ++i) {
            const int oa = (q * 128 + wm * 64 + i * 16 + ln15) * 8;
            const int ob = (q * 128 + wn * 64 + i * 16 + ln15) * 8;
            fah[i] = *(const short8*)&sAh[oa];
            fal[i] = *(const short8*)&sAl[oa];
            fbh[i] = *(const short8*)&sBh[ob];
            fbl[i] = *(const short8*)&sBl[ob];
        }
        #pragma unroll
        for (int mt = 0; mt < 4; ++mt)
            #pragma unroll
            for (int nt = 0; nt < 4; ++nt) {
                acc[mt][nt] = __builtin_amdgcn_mfma_f32_16x16x32_bf16(
                    fah[mt], fbh[nt], acc[mt][nt], 0, 0, 0);
                acc[mt][nt] = __builtin_amdgcn_mfma_f32_16x16x32_bf16(
                    fah[mt], fbl[nt], acc[mt][nt], 0, 0, 0);
                acc[mt][nt] = __builtin_amdgcn_mfma_f32_16x16x32_bf16(
                    fal[mt], fbh[nt], acc[mt][nt], 0, 0, 0);
            }
        __syncthreads();
    }

    // epilogue: C/D layout col=lane&15, row=q*4+reg
    #pragma unroll
    for (int mt = 0; mt < 4; ++mt) {
        const int rowb = m0 + wm * 64 + mt * 16 + q * 4;
        #pragma unroll
        for (int nt = 0; nt < 4; ++nt) {
            const int col = n0 + wn * 64 + nt * 16 + ln15;
            #pragma unroll
            for (int r = 0; r < 4; ++r)
                C[(size_t)(rowb + r) * ldc + col] = acc[mt][nt][r];
        }
    }
}

// ---------------------------------------------------------------------------
// fp32 NT-GEMM (small GEMMs only). MODE 0: plain. MODE 1: softplus(c+bias).
// LDS rows padded 64->68 to break the 4-way write bank conflict.
// ---------------------------------------------------------------------------
template<int MODE>
__global__ __launch_bounds__(256)
void gemm_nt(const float* __restrict__ A, int lda,
             const float* __restrict__ Bm, int ldb,
             float* __restrict__ C, int ldc,
             int M, int N, int K,
             const float* __restrict__ bias)
{
    __shared__ float As[16][68];
    __shared__ float Bs[16][68];
    const int m0 = blockIdx.x * 64;
    const int n0 = blockIdx.y * 64;
    const int tid = threadIdx.x;
    const int tm = tid >> 4;
    const int tn = tid & 15;
    const int lrow = tid >> 2;
    const int lk   = (tid & 3) << 2;

    float acc[4][4] = {{0.f}};

    for (int k0 = 0; k0 < K; k0 += 16) {
        float4 a4 = *(const float4*)(A + (size_t)(m0 + lrow) * lda + (k0 + lk));
        float4 b4 = make_float4(0.f, 0.f, 0.f, 0.f);
        if (n0 + lrow < N)
            b4 = *(const float4*)(Bm + (size_t)(n0 + lrow) * ldb + (k0 + lk));
        As[lk+0][lrow] = a4.x; As[lk+1][lrow] = a4.y;
        As[lk+2][lrow] = a4.z; As[lk+3][lrow] = a4.w;
        Bs[lk+0][lrow] = b4.x; Bs[lk+1][lrow] = b4.y;
        Bs[lk+2][lrow] = b4.z; Bs[lk+3][lrow] = b4.w;
        __syncthreads();
        #pragma unroll
        for (int kk = 0; kk < 16; ++kk) {
            float4 av = *(const float4*)&As[kk][tm << 2];
            float4 bv = *(const float4*)&Bs[kk][tn << 2];
            float am[4] = {av.x, av.y, av.z, av.w};
            float bn[4] = {bv.x, bv.y, bv.z, bv.w};
            #pragma unroll
            for (int i = 0; i < 4; ++i)
                #pragma unroll
                for (int j = 0; j < 4; ++j)
                    acc[i][j] = fmaf(am[i], bn[j], acc[i][j]);
        }
        __syncthreads();
    }

    #pragma unroll
    for (int i = 0; i < 4; ++i) {
        const int row = m0 + (tm << 2) + i;
        #pragma unroll
        for (int j = 0; j < 4; ++j) {
            const int col = n0 + (tn << 2) + j;
            if (col < N) {
                float v = acc[i][j];
                if (MODE == 1) {
                    v += bias[col];
                    v = (v > 20.f) ? v : log1pf(__expf(v));
                }
                C[(size_t)row * ldc + col] = v;
            }
        }
    }
}

// ---------------------------------------------------------------------------
// Depthwise causal conv (k=4) over the u half of xz, then SiLU.
// ---------------------------------------------------------------------------
__global__ __launch_bounds__(256)
void conv_silu(const float* __restrict__ xz,
               const float* __restrict__ conv_w,
               float* __restrict__ u_act)
{
    const int idx = blockIdx.x * 256 + threadIdx.x;
    const int d  = idx & (INNER - 1);
    const int t  = (idx >> 11) & (LL - 1);
    const int bb = idx >> 22;
    float s = 0.f;
    #pragma unroll
    for (int j = 0; j < KCONV; ++j) {
        const int ts = t + j - (KCONV - 1);
        if (ts >= 0)
            s = fmaf(xz[((size_t)(bb * LL + ts)) * (2 * INNER) + d],
                     conv_w[d * KCONV + j], s);
    }
    u_act[idx] = s / (1.f + __expf(-s));
}

// ---------------------------------------------------------------------------
// Scan pass 1: per-chunk summaries (h[16] in registers per thread-channel).
// ---------------------------------------------------------------------------
__global__ __launch_bounds__(256)
void scan_pass1(const float* __restrict__ u_act,
                const float* __restrict__ dtb,
                const float* __restrict__ params,
                const float* __restrict__ log_A,
                float* __restrict__ Hout,
                float* __restrict__ sumdt_out)
{
    const int bid = blockIdx.x;
    const int c   = bid & (SCH - 1);
    const int cg  = (bid >> 6) & 7;
    const int b   = bid >> 9;
    const int tid = threadIdx.x;
    const int d   = cg * 256 + tid;
    const size_t rowbase = (size_t)b * LL + (size_t)c * TCH;

    float A[NST];
    #pragma unroll
    for (int n = 0; n < NST; n += 4) {
        float4 v = *(const float4*)(log_A + (size_t)d * NST + n);
        A[n+0] = -__expf(v.x); A[n+1] = -__expf(v.y);
        A[n+2] = -__expf(v.z); A[n+3] = -__expf(v.w);
    }

    __shared__ float Bs[TCH * NST];
    for (int i = tid; i < TCH * NST; i += 256) {
        const int t = i >> 4, j = i & 15;
        Bs[i] = params[(rowbase + t) * 96 + DRANK + j];
    }
    __syncthreads();

    float h[NST];
    #pragma unroll
    for (int n = 0; n < NST; ++n) h[n] = 0.f;
    float sdt = 0.f;

    #pragma unroll 4
    for (int t = 0; t < TCH; ++t) {
        const float dtv = dtb[(rowbase + t) * INNER + d];
        const float uv  = u_act[(rowbase + t) * INNER + d];
        const float du = dtv * uv;
        sdt += dtv;
        const float4* Bp = (const float4*)&Bs[t * NST];
        const float4 B0 = Bp[0], B1 = Bp[1], B2 = Bp[2], B3 = Bp[3];
        const float Bv[NST] = {B0.x,B0.y,B0.z,B0.w, B1.x,B1.y,B1.z,B1.w,
                               B2.x,B2.y,B2.z,B2.w, B3.x,B3.y,B3.z,B3.w};
        #pragma unroll
        for (int n = 0; n < NST; ++n)
            h[n] = fmaf(__expf(dtv * A[n]), h[n], du * Bv[n]);
    }

    const size_t o = ((size_t)(b * SCH + c) * INNER + d) * NST;
    #pragma unroll
    for (int n = 0; n < NST; n += 4)
        *(float4*)(Hout + o + n) = make_float4(h[n], h[n+1], h[n+2], h[n+3]);
    sumdt_out[(size_t)(b * SCH + c) * INNER + d] = sdt;
}

// ---------------------------------------------------------------------------
// Scan pass 2: serial combine over chunks. One thread = one (b,d,n).
// ---------------------------------------------------------------------------
__global__ __launch_bounds__(256)
void scan_pass2(const float* __restrict__ Hbuf,
                const float* __restrict__ sumdt,
                const float* __restrict__ log_A,
                float* __restrict__ hinit)
{
    const int idx = blockIdx.x * 256 + threadIdx.x;
    const int n = idx & 15;
    const int d = (idx >> 4) & (INNER - 1);
    const int b = idx >> 15;
    const float An = -__expf(log_A[(size_t)d * NST + n]);
    float h = 0.f;
    for (int c = 0; c < SCH; ++c) {
        const size_t o = ((size_t)(b * SCH + c) * INNER + d) * NST + n;
        hinit[o] = h;
        const float P = __expf(An * sumdt[(size_t)(b * SCH + c) * INNER + d]);
        h = Hbuf[o] + P * h;
    }
}

// ---------------------------------------------------------------------------
// Scan pass 3: re-scan each chunk from h_init, fused epilogue:
// yg = (y + u*D) * silu(gate); writes into the dead u-half of xz.
// ---------------------------------------------------------------------------
__global__ __launch_bounds__(256)
void scan_pass3(const float* __restrict__ u_act,
                const float* __restrict__ dtb,
                const float* __restrict__ params,
                const float* __restrict__ xz,
                const float* __restrict__ log_A,
                const float* __restrict__ Dv,
                const float* __restrict__ hinit,
                float* __restrict__ yg, int ldy)
{
    const int bid = blockIdx.x;
    const int c   = bid & (SCH - 1);
    const int cg  = (bid >> 6) & 7;
    const int b   = bid >> 9;
    const int tid = threadIdx.x;
    const int d   = cg * 256 + tid;
    const size_t rowbase = (size_t)b * LL + (size_t)c * TCH;

    float A[NST];
    #pragma unroll
    for (int n = 0; n < NST; n += 4) {
        float4 v = *(const float4*)(log_A + (size_t)d * NST + n);
        A[n+0] = -__expf(v.x); A[n+1] = -__expf(v.y);
        A[n+2] = -__expf(v.z); A[n+3] = -__expf(v.w);
    }
    const float Dd = Dv[d];

    __shared__ float BCs[TCH * 32];
    for (int i = tid; i < TCH * 32; i += 256) {
        const int t = i >> 5, j = i & 31;
        BCs[i] = params[(rowbase + t) * 96 + DRANK + j];
    }

    float h[NST];
    {
        const size_t o = ((size_t)(b * SCH + c) * INNER + d) * NST;
        #pragma unroll
        for (int n = 0; n < NST; n += 4) {
            float4 v = *(const float4*)(hinit + o + n);
            h[n] = v.x; h[n+1] = v.y; h[n+2] = v.z; h[n+3] = v.w;
        }
    }
    __syncthreads();

    #pragma unroll 2
    for (int t = 0; t < TCH; ++t) {
        const float dtv = dtb[(rowbase + t) * INNER + d];
        const float uv  = u_act[(rowbase + t) * INNER + d];
        const float gv  = xz[(rowbase + t) * (2 * INNER) + INNER + d];
        const float du = dtv * uv;
        const float4* Bp = (const float4*)&BCs[t * 32];
        const float4 B0 = Bp[0], B1 = Bp[1], B2 = Bp[2], B3 = Bp[3];
        const float4 C0 = Bp[4], C1 = Bp[5], C2 = Bp[6], C3 = Bp[7];
        const float Bv[NST] = {B0.x,B0.y,B0.z,B0.w, B1.x,B1.y,B1.z,B1.w,
                               B2.x,B2.y,B2.z,B2.w, B3.x,B3.y,B3.z,B3.w};
        const float Cv[NST] = {C0.x,C0.y,C0.z,C0.w, C1.x,C1.y,C1.z,C1.w,
                               C2.x,C2.y,C2.z,C2.w, C3.x,C3.y,C3.z,C3.w};
        #pragma unroll
        for (int n = 0; n < NST; ++n)
            h[n] = fmaf(__expf(dtv * A[n]), h[n], du * Bv[n]);
        float p[8];
        #pragma unroll
        for (int n = 0; n < 8; ++n)
            p[n] = fmaf(h[n], Cv[n], h[n+8] * Cv[n+8]);
        const float y = ((p[0]+p[1]) + (p[2]+p[3])) + ((p[4]+p[5]) + (p[6]+p[7]));
        const float sg = gv / (1.f + __expf(-gv));
        yg[(rowbase + t) * ldy + d] = (y + uv * Dd) * sg;
    }
}

// ---------------------------------------------------------------------------
extern "C" void kernel_launch(void* const* d_in, const int* in_sizes, int n_in,
                              void* d_out, int out_size, void* d_ws, size_t ws_size,
                              hipStream_t stream)
{
    const float* x     = (const float*)d_in[0];
    const float* W_in  = (const float*)d_in[1];
    const float* convw = (const float*)d_in[2];
    const float* W_ssm = (const float*)d_in[3];
    const float* W_dt  = (const float*)d_in[4];
    const float* b_dt  = (const float*)d_in[5];
    const float* log_A = (const float*)d_in[6];
    const float* Dv    = (const float*)d_in[7];
    const float* W_out = (const float*)d_in[8];
    float* out = (float*)d_out;

    float* ws = (float*)d_ws;
    float* xz     = ws;                                   // 16M floats
    float* u_act  = xz     + (size_t)MROWS * 2 * INNER;   // 8M
    float* dt_buf = u_act  + (size_t)MROWS * INNER;       // 8M
    float* params = dt_buf + (size_t)MROWS * INNER;       // 384K
    float* Hbuf   = params + (size_t)MROWS * 96;          // 4M
    float* hinit  = Hbuf   + (size_t)BB * SCH * INNER * NST;  // 4M
    float* sumdt  = hinit  + (size_t)BB * SCH * INNER * NST;  // 256K
    // bf16 split region (aliased between phase A and phase B)
    unsigned short* splits = (unsigned short*)(sumdt + (size_t)BB * SCH * INNER);
    // phase A: x / W_in splits (each 4M ushorts)
    unsigned short* x_hi   = splits;
    unsigned short* x_lo   = x_hi   + (size_t)MROWS * DMODEL;
    unsigned short* win_hi = x_lo   + (size_t)MROWS * DMODEL;
    unsigned short* win_lo = win_hi + (size_t)(2 * INNER) * DMODEL;
    // phase B (after GEMM1 done): yg / W_out splits
    unsigned short* yg_hi   = splits;
    unsigned short* yg_lo   = yg_hi   + (size_t)MROWS * INNER;
    unsigned short* wout_hi = yg_lo   + (size_t)MROWS * INNER;
    unsigned short* wout_lo = wout_hi + (size_t)DMODEL * INNER;

    // --- phase A splits: x [4096,1024], W_in [4096,1024]
    split_bf16<<<(MROWS * DMODEL / 4 + 255) / 256, 256, 0, stream>>>(
        x, DMODEL, DMODEL / 4, x_hi, x_lo, MROWS * DMODEL / 4);
    split_bf16<<<(2 * INNER * DMODEL / 4 + 255) / 256, 256, 0, stream>>>(
        W_in, DMODEL, DMODEL / 4, win_hi, win_lo, 2 * INNER * DMODEL / 4);

    // 1. xz = x @ W_in.T   (bf16x3 MFMA)  M=4096 N=4096 K=1024
    gemm_bf16x3<<<dim3(MROWS / 128, (2 * INNER) / 128), 256, 0, stream>>>(
        x_hi, x_lo, DMODEL, win_hi, win_lo, DMODEL, xz, 2 * INNER, DMODEL);

    // 2. u_act = silu(causal_conv(u))
    conv_silu<<<(MROWS * INNER) / 256, 256, 0, stream>>>(xz, convw, u_act);

    // 3. params = u_act @ W_ssm.T          M=4096 N=96 K=2048
    gemm_nt<0><<<dim3(64, 2), 256, 0, stream>>>(
        u_act, INNER, W_ssm, INNER, params, 96,
        MROWS, 96, INNER, nullptr);

    // 4. dt = softplus(d_low @ W_dt.T + b_dt)  M=4096 N=2048 K=64 (lda=96)
    gemm_nt<1><<<dim3(64, 32), 256, 0, stream>>>(
        params, 96, W_dt, DRANK, dt_buf, INNER,
        MROWS, INNER, DRANK, b_dt);

    // 5. chunked selective scan (3 passes); yg -> u-half of xz (ld 4096)
    scan_pass1<<<BB * (INNER / 256) * SCH, 256, 0, stream>>>(
        u_act, dt_buf, params, log_A, Hbuf, sumdt);
    scan_pass2<<<BB * INNER * NST / 256, 256, 0, stream>>>(
        Hbuf, sumdt, log_A, hinit);
    scan_pass3<<<BB * (INNER / 256) * SCH, 256, 0, stream>>>(
        u_act, dt_buf, params, xz, log_A, Dv, hinit, xz, 2 * INNER);

    // --- phase B splits: yg (strided in xz, ld 4096) and W_out [1024,2048]
    split_bf16<<<(MROWS * INNER / 4 + 255) / 256, 256, 0, stream>>>(
        xz, 2 * INNER, INNER / 4, yg_hi, yg_lo, MROWS * INNER / 4);
    split_bf16<<<(DMODEL * INNER / 4 + 255) / 256, 256, 0, stream>>>(
        W_out, INNER, INNER / 4, wout_hi, wout_lo, DMODEL * INNER / 4);

    // 6. out = yg @ W_out.T  (bf16x3 MFMA)  M=4096 N=1024 K=2048
    gemm_bf16x3<<<dim3(MROWS / 128, DMODEL / 128), 256, 0, stream>>>(
        yg_hi, yg_lo, INNER, wout_hi, wout_lo, INNER, out, DMODEL, INNER);
}

// Round 4
// 473.860 us; speedup vs baseline: 3.3078x; 1.4117x over previous
//
#include <hip/hip_runtime.h>
#include <cstdint>
#include <cstddef>

// Problem constants (fixed by setup_inputs)
#define BB     2
#define LL     2048
#define DMODEL 1024
#define INNER  2048
#define NST    16
#define KCONV  4
#define DRANK  64
#define MROWS  (BB*LL)   // 4096
#define SCH    64        // time chunks
#define TCH    (LL/SCH)  // 32 timesteps per chunk

typedef __attribute__((ext_vector_type(8))) _Float16 half8;   // 8 fp16 = 4 VGPRs
typedef __attribute__((ext_vector_type(4))) _Float16 half4;
typedef __attribute__((ext_vector_type(4))) float floatx4;

// async global->LDS, 16B per lane, dest = wave-uniform base + lane*16
#define GLL(gp, lp) __builtin_amdgcn_global_load_lds( \
    (const __attribute__((address_space(1))) unsigned int*)(gp), \
    (__attribute__((address_space(3))) unsigned int*)(lp), 16, 0, 0)

// ---------------------------------------------------------------------------
// fp32 -> fp16 convert (contiguous), 4 elems/thread
// ---------------------------------------------------------------------------
__global__ __launch_bounds__(256)
void cvt_f16(const float* __restrict__ in, _Float16* __restrict__ out, int n4)
{
    const int idx = blockIdx.x * 256 + threadIdx.x;
    if (idx >= n4) return;
    const float4 v = ((const float4*)in)[idx];
    half4 h;
    h.x = (_Float16)v.x; h.y = (_Float16)v.y;
    h.z = (_Float16)v.z; h.w = (_Float16)v.w;
    *(half4*)(out + (size_t)idx * 4) = h;
}

// ---------------------------------------------------------------------------
// fp16 MFMA NT-GEMM: C[M,N] = A[M,K] @ B[N,K]^T, fp32 accumulate/output.
// 128x128 tile, 4 waves, each 4x4 tiles of mfma_f32_16x16x32_f16, BK=32.
// LDS k-group-major: [kq 0..3][row 0..127][8 fp16]. M,N%128==0, K%32==0.
// ---------------------------------------------------------------------------
__global__ __launch_bounds__(256)
void gemm_f16(const _Float16* __restrict__ A, int lda,
              const _Float16* __restrict__ B, int ldb,
              float* __restrict__ C, int ldc, int K)
{
    __shared__ __align__(16) _Float16 sA[4 * 128 * 8];
    __shared__ __align__(16) _Float16 sB[4 * 128 * 8];

    const int tid  = threadIdx.x;
    const int w    = tid >> 6;        // wave 0..3 (owns k-group w)
    const int lane = tid & 63;
    const int ln15 = lane & 15;
    const int q    = lane >> 4;       // k-quad 0..3
    const int wm   = w & 1, wn = w >> 1;
    const int m0 = blockIdx.x * 128, n0 = blockIdx.y * 128;

    floatx4 acc[4][4];
    #pragma unroll
    for (int i = 0; i < 4; ++i)
        #pragma unroll
        for (int j = 0; j < 4; ++j)
            acc[i][j] = (floatx4){0.f, 0.f, 0.f, 0.f};

    const size_t a0 = (size_t)(m0 + lane) * lda;
    const size_t a1 = (size_t)(m0 + 64 + lane) * lda;
    const size_t b0 = (size_t)(n0 + lane) * ldb;
    const size_t b1 = (size_t)(n0 + 64 + lane) * ldb;

    _Float16* la0 = &sA[(w * 128 +  0) * 8];
    _Float16* la1 = &sA[(w * 128 + 64) * 8];
    _Float16* lb0 = &sB[(w * 128 +  0) * 8];
    _Float16* lb1 = &sB[(w * 128 + 64) * 8];

    for (int k0 = 0; k0 < K; k0 += 32) {
        const int kg = k0 + w * 8;
        GLL(A + a0 + kg, la0);
        GLL(A + a1 + kg, la1);
        GLL(B + b0 + kg, lb0);
        GLL(B + b1 + kg, lb1);
        __syncthreads();

        half8 fa[4], fb[4];
        #pragma unroll
        for (int i = 0; i < 4; ++i) {
            fa[i] = *(const half8*)&sA[(q * 128 + wm * 64 + i * 16 + ln15) * 8];
            fb[i] = *(const half8*)&sB[(q * 128 + wn * 64 + i * 16 + ln15) * 8];
        }
        #pragma unroll
        for (int mt = 0; mt < 4; ++mt)
            #pragma unroll
            for (int nt = 0; nt < 4; ++nt)
                acc[mt][nt] = __builtin_amdgcn_mfma_f32_16x16x32_f16(
                    fa[mt], fb[nt], acc[mt][nt], 0, 0, 0);
        __syncthreads();
    }

    // epilogue: C/D layout col=lane&15, row=q*4+reg
    #pragma unroll
    for (int mt = 0; mt < 4; ++mt) {
        const int rowb = m0 + wm * 64 + mt * 16 + q * 4;
        #pragma unroll
        for (int nt = 0; nt < 4; ++nt) {
            const int col = n0 + wn * 64 + nt * 16 + ln15;
            #pragma unroll
            for (int r = 0; r < 4; ++r)
                C[(size_t)(rowb + r) * ldc + col] = acc[mt][nt][r];
        }
    }
}

// ---------------------------------------------------------------------------
// fp32 NT-GEMM. MODE 0: plain. MODE 1: softplus(c+bias). MODE 2: atomicAdd
// (split-K over blockIdx.z; C must be pre-zeroed). LDS rows padded to 68.
// ---------------------------------------------------------------------------
template<int MODE>
__global__ __launch_bounds__(256)
void gemm_nt(const float* __restrict__ A, int lda,
             const float* __restrict__ Bm, int ldb,
             float* __restrict__ C, int ldc,
             int M, int N, int K, int kchunk,
             const float* __restrict__ bias)
{
    __shared__ float As[16][68];
    __shared__ float Bs[16][68];
    const int m0 = blockIdx.x * 64;
    const int n0 = blockIdx.y * 64;
    const int kbeg = blockIdx.z * kchunk;
    const int kend = kbeg + kchunk;
    const int tid = threadIdx.x;
    const int tm = tid >> 4;
    const int tn = tid & 15;
    const int lrow = tid >> 2;
    const int lk   = (tid & 3) << 2;

    float acc[4][4] = {{0.f}};

    for (int k0 = kbeg; k0 < kend; k0 += 16) {
        float4 a4 = *(const float4*)(A + (size_t)(m0 + lrow) * lda + (k0 + lk));
        float4 b4 = make_float4(0.f, 0.f, 0.f, 0.f);
        if (n0 + lrow < N)
            b4 = *(const float4*)(Bm + (size_t)(n0 + lrow) * ldb + (k0 + lk));
        As[lk+0][lrow] = a4.x; As[lk+1][lrow] = a4.y;
        As[lk+2][lrow] = a4.z; As[lk+3][lrow] = a4.w;
        Bs[lk+0][lrow] = b4.x; Bs[lk+1][lrow] = b4.y;
        Bs[lk+2][lrow] = b4.z; Bs[lk+3][lrow] = b4.w;
        __syncthreads();
        #pragma unroll
        for (int kk = 0; kk < 16; ++kk) {
            float4 av = *(const float4*)&As[kk][tm << 2];
            float4 bv = *(const float4*)&Bs[kk][tn << 2];
            float am[4] = {av.x, av.y, av.z, av.w};
            float bn[4] = {bv.x, bv.y, bv.z, bv.w};
            #pragma unroll
            for (int i = 0; i < 4; ++i)
                #pragma unroll
                for (int j = 0; j < 4; ++j)
                    acc[i][j] = fmaf(am[i], bn[j], acc[i][j]);
        }
        __syncthreads();
    }

    #pragma unroll
    for (int i = 0; i < 4; ++i) {
        const int row = m0 + (tm << 2) + i;
        #pragma unroll
        for (int j = 0; j < 4; ++j) {
            const int col = n0 + (tn << 2) + j;
            if (col < N) {
                float v = acc[i][j];
                if (MODE == 1) {
                    v += bias[col];
                    v = (v > 20.f) ? v : log1pf(__expf(v));
                }
                if (MODE == 2)
                    atomicAdd(&C[(size_t)row * ldc + col], v);
                else
                    C[(size_t)row * ldc + col] = v;
            }
        }
    }
}

// ---------------------------------------------------------------------------
// Depthwise causal conv (k=4) over the u half of xz, then SiLU.
// ---------------------------------------------------------------------------
__global__ __launch_bounds__(256)
void conv_silu(const float* __restrict__ xz,
               const float* __restrict__ conv_w,
               float* __restrict__ u_act)
{
    const int idx = blockIdx.x * 256 + threadIdx.x;
    const int d  = idx & (INNER - 1);
    const int t  = (idx >> 11) & (LL - 1);
    const int bb = idx >> 22;
    float s = 0.f;
    #pragma unroll
    for (int j = 0; j < KCONV; ++j) {
        const int ts = t + j - (KCONV - 1);
        if (ts >= 0)
            s = fmaf(xz[((size_t)(bb * LL + ts)) * (2 * INNER) + d],
                     conv_w[d * KCONV + j], s);
    }
    u_act[idx] = s / (1.f + __expf(-s));
}

// ---------------------------------------------------------------------------
// Scan pass 1: per-chunk summaries (h[16] in registers per thread-channel).
// ---------------------------------------------------------------------------
__global__ __launch_bounds__(256)
void scan_pass1(const float* __restrict__ u_act,
                const float* __restrict__ dtb,
                const float* __restrict__ params,
                const float* __restrict__ log_A,
                float* __restrict__ Hout,
                float* __restrict__ sumdt_out)
{
    const int bid = blockIdx.x;
    const int c   = bid & (SCH - 1);
    const int cg  = (bid >> 6) & 7;
    const int b   = bid >> 9;
    const int tid = threadIdx.x;
    const int d   = cg * 256 + tid;
    const size_t rowbase = (size_t)b * LL + (size_t)c * TCH;

    float A[NST];
    #pragma unroll
    for (int n = 0; n < NST; n += 4) {
        float4 v = *(const float4*)(log_A + (size_t)d * NST + n);
        A[n+0] = -__expf(v.x); A[n+1] = -__expf(v.y);
        A[n+2] = -__expf(v.z); A[n+3] = -__expf(v.w);
    }

    __shared__ float Bs[TCH * NST];
    for (int i = tid; i < TCH * NST; i += 256) {
        const int t = i >> 4, j = i & 15;
        Bs[i] = params[(rowbase + t) * 96 + DRANK + j];
    }
    __syncthreads();

    float h[NST];
    #pragma unroll
    for (int n = 0; n < NST; ++n) h[n] = 0.f;
    float sdt = 0.f;

    #pragma unroll 4
    for (int t = 0; t < TCH; ++t) {
        const float dtv = dtb[(rowbase + t) * INNER + d];
        const float uv  = u_act[(rowbase + t) * INNER + d];
        const float du = dtv * uv;
        sdt += dtv;
        const float4* Bp = (const float4*)&Bs[t * NST];
        const float4 B0 = Bp[0], B1 = Bp[1], B2 = Bp[2], B3 = Bp[3];
        const float Bv[NST] = {B0.x,B0.y,B0.z,B0.w, B1.x,B1.y,B1.z,B1.w,
                               B2.x,B2.y,B2.z,B2.w, B3.x,B3.y,B3.z,B3.w};
        #pragma unroll
        for (int n = 0; n < NST; ++n)
            h[n] = fmaf(__expf(dtv * A[n]), h[n], du * Bv[n]);
    }

    const size_t o = ((size_t)(b * SCH + c) * INNER + d) * NST;
    #pragma unroll
    for (int n = 0; n < NST; n += 4)
        *(float4*)(Hout + o + n) = make_float4(h[n], h[n+1], h[n+2], h[n+3]);
    sumdt_out[(size_t)(b * SCH + c) * INNER + d] = sdt;
}

// ---------------------------------------------------------------------------
// Scan pass 2: serial combine over chunks. One thread = one (b,d,n).
// ---------------------------------------------------------------------------
__global__ __launch_bounds__(256)
void scan_pass2(const float* __restrict__ Hbuf,
                const float* __restrict__ sumdt,
                const float* __restrict__ log_A,
                float* __restrict__ hinit)
{
    const int idx = blockIdx.x * 256 + threadIdx.x;
    const int n = idx & 15;
    const int d = (idx >> 4) & (INNER - 1);
    const int b = idx >> 15;
    const float An = -__expf(log_A[(size_t)d * NST + n]);
    float h = 0.f;
    for (int c = 0; c < SCH; ++c) {
        const size_t o = ((size_t)(b * SCH + c) * INNER + d) * NST + n;
        hinit[o] = h;
        const float P = __expf(An * sumdt[(size_t)(b * SCH + c) * INNER + d]);
        h = Hbuf[o] + P * h;
    }
}

// ---------------------------------------------------------------------------
// Scan pass 3: re-scan each chunk from h_init, fused epilogue:
// yg = (y + u*D) * silu(gate), written DIRECTLY as fp16 (feeds GEMM3).
// ---------------------------------------------------------------------------
__global__ __launch_bounds__(256)
void scan_pass3(const float* __restrict__ u_act,
                const float* __restrict__ dtb,
                const float* __restrict__ params,
                const float* __restrict__ xz,     // gate at col INNER+d
                const float* __restrict__ log_A,
                const float* __restrict__ Dv,
                const float* __restrict__ hinit,
                _Float16* __restrict__ yg16)      // [M, INNER]
{
    const int bid = blockIdx.x;
    const int c   = bid & (SCH - 1);
    const int cg  = (bid >> 6) & 7;
    const int b   = bid >> 9;
    const int tid = threadIdx.x;
    const int d   = cg * 256 + tid;
    const size_t rowbase = (size_t)b * LL + (size_t)c * TCH;

    float A[NST];
    #pragma unroll
    for (int n = 0; n < NST; n += 4) {
        float4 v = *(const float4*)(log_A + (size_t)d * NST + n);
        A[n+0] = -__expf(v.x); A[n+1] = -__expf(v.y);
        A[n+2] = -__expf(v.z); A[n+3] = -__expf(v.w);
    }
    const float Dd = Dv[d];

    __shared__ float BCs[TCH * 32];
    for (int i = tid; i < TCH * 32; i += 256) {
        const int t = i >> 5, j = i & 31;
        BCs[i] = params[(rowbase + t) * 96 + DRANK + j];
    }

    float h[NST];
    {
        const size_t o = ((size_t)(b * SCH + c) * INNER + d) * NST;
        #pragma unroll
        for (int n = 0; n < NST; n += 4) {
            float4 v = *(const float4*)(hinit + o + n);
            h[n] = v.x; h[n+1] = v.y; h[n+2] = v.z; h[n+3] = v.w;
        }
    }
    __syncthreads();

    #pragma unroll 2
    for (int t = 0; t < TCH; ++t) {
        const float dtv = dtb[(rowbase + t) * INNER + d];
        const float uv  = u_act[(rowbase + t) * INNER + d];
        const float gv  = xz[(rowbase + t) * (2 * INNER) + INNER + d];
        const float du = dtv * uv;
        const float4* Bp = (const float4*)&BCs[t * 32];
        const float4 B0 = Bp[0], B1 = Bp[1], B2 = Bp[2], B3 = Bp[3];
        const float4 C0 = Bp[4], C1 = Bp[5], C2 = Bp[6], C3 = Bp[7];
        const float Bv[NST] = {B0.x,B0.y,B0.z,B0.w, B1.x,B1.y,B1.z,B1.w,
                               B2.x,B2.y,B2.z,B2.w, B3.x,B3.y,B3.z,B3.w};
        const float Cv[NST] = {C0.x,C0.y,C0.z,C0.w, C1.x,C1.y,C1.z,C1.w,
                               C2.x,C2.y,C2.z,C2.w, C3.x,C3.y,C3.z,C3.w};
        #pragma unroll
        for (int n = 0; n < NST; ++n)
            h[n] = fmaf(__expf(dtv * A[n]), h[n], du * Bv[n]);
        float p[8];
        #pragma unroll
        for (int n = 0; n < 8; ++n)
            p[n] = fmaf(h[n], Cv[n], h[n+8] * Cv[n+8]);
        const float y = ((p[0]+p[1]) + (p[2]+p[3])) + ((p[4]+p[5]) + (p[6]+p[7]));
        const float sg = gv / (1.f + __expf(-gv));
        yg16[(rowbase + t) * INNER + d] = (_Float16)((y + uv * Dd) * sg);
    }
}

// ---------------------------------------------------------------------------
extern "C" void kernel_launch(void* const* d_in, const int* in_sizes, int n_in,
                              void* d_out, int out_size, void* d_ws, size_t ws_size,
                              hipStream_t stream)
{
    const float* x     = (const float*)d_in[0];
    const float* W_in  = (const float*)d_in[1];
    const float* convw = (const float*)d_in[2];
    const float* W_ssm = (const float*)d_in[3];
    const float* W_dt  = (const float*)d_in[4];
    const float* b_dt  = (const float*)d_in[5];
    const float* log_A = (const float*)d_in[6];
    const float* Dv    = (const float*)d_in[7];
    const float* W_out = (const float*)d_in[8];
    float* out = (float*)d_out;

    float* ws = (float*)d_ws;
    float* xz     = ws;                                       // 16M floats
    float* u_act  = xz     + (size_t)MROWS * 2 * INNER;       // 8M
    float* dt_buf = u_act  + (size_t)MROWS * INNER;           // 8M
    float* params = dt_buf + (size_t)MROWS * INNER;           // 393216
    float* Hbuf   = params + (size_t)MROWS * 96;              // 4.19M
    float* hinit  = Hbuf   + (size_t)BB * SCH * INNER * NST;  // 4.19M
    float* sumdt  = hinit  + (size_t)BB * SCH * INNER * NST;  // 262144
    _Float16* x16    = (_Float16*)(sumdt + (size_t)BB * SCH * INNER);
    _Float16* win16  = x16   + (size_t)MROWS * DMODEL;        // 4M halfs each
    _Float16* wout16 = win16 + (size_t)(2 * INNER) * DMODEL;
    _Float16* yg16   = wout16 + (size_t)DMODEL * INNER;       // 8M halfs

    // fp32 -> fp16 converts (contiguous)
    cvt_f16<<<(MROWS * DMODEL / 4) / 256, 256, 0, stream>>>(
        x, x16, MROWS * DMODEL / 4);
    cvt_f16<<<(2 * INNER * DMODEL / 4) / 256, 256, 0, stream>>>(
        W_in, win16, 2 * INNER * DMODEL / 4);
    cvt_f16<<<(DMODEL * INNER / 4) / 256, 256, 0, stream>>>(
        W_out, wout16, DMODEL * INNER / 4);

    // 1. xz = x @ W_in.T   (fp16 MFMA)  M=4096 N=4096 K=1024
    gemm_f16<<<dim3(MROWS / 128, (2 * INNER) / 128), 256, 0, stream>>>(
        x16, DMODEL, win16, DMODEL, xz, 2 * INNER, DMODEL);

    // 2. u_act = silu(causal_conv(u))
    conv_silu<<<(MROWS * INNER) / 256, 256, 0, stream>>>(xz, convw, u_act);

    // 3. params = u_act @ W_ssm.T  (split-K x4, atomic)  M=4096 N=96 K=2048
    hipMemsetAsync(params, 0, (size_t)MROWS * 96 * sizeof(float), stream);
    gemm_nt<2><<<dim3(64, 2, 4), 256, 0, stream>>>(
        u_act, INNER, W_ssm, INNER, params, 96,
        MROWS, 96, INNER, INNER / 4, nullptr);

    // 4. dt = softplus(d_low @ W_dt.T + b_dt)  M=4096 N=2048 K=64 (lda=96)
    gemm_nt<1><<<dim3(64, 32), 256, 0, stream>>>(
        params, 96, W_dt, DRANK, dt_buf, INNER,
        MROWS, INNER, DRANK, DRANK, b_dt);

    // 5. chunked selective scan (3 passes); pass3 emits fp16 yg
    scan_pass1<<<BB * (INNER / 256) * SCH, 256, 0, stream>>>(
        u_act, dt_buf, params, log_A, Hbuf, sumdt);
    scan_pass2<<<BB * INNER * NST / 256, 256, 0, stream>>>(
        Hbuf, sumdt, log_A, hinit);
    scan_pass3<<<BB * (INNER / 256) * SCH, 256, 0, stream>>>(
        u_act, dt_buf, params, xz, log_A, Dv, hinit, yg16);

    // 6. out = yg @ W_out.T  (fp16 MFMA)  M=4096 N=1024 K=2048
    gemm_f16<<<dim3(MROWS / 128, DMODEL / 128), 256, 0, stream>>>(
        yg16, INNER, wout16, INNER, out, DMODEL, INNER);
}

// Round 5
// 420.030 us; speedup vs baseline: 3.7317x; 1.1282x over previous
//
#include <hip/hip_runtime.h>
#include <cstdint>
#include <cstddef>

// Problem constants (fixed by setup_inputs)
#define BB     2
#define LL     2048
#define DMODEL 1024
#define INNER  2048
#define NST    16
#define KCONV  4
#define DRANK  64
#define MROWS  (BB*LL)   // 4096
#define SCH    64        // time chunks
#define TCH    (LL/SCH)  // 32 timesteps per chunk

typedef __attribute__((ext_vector_type(8))) _Float16 half8;   // 8 fp16 = 4 VGPRs
typedef __attribute__((ext_vector_type(4))) _Float16 half4;
typedef __attribute__((ext_vector_type(4))) float floatx4;

// async global->LDS, 16B per lane, dest = wave-uniform base + lane*16
#define GLL(gp, lp) __builtin_amdgcn_global_load_lds( \
    (const __attribute__((address_space(1))) unsigned int*)(gp), \
    (__attribute__((address_space(3))) unsigned int*)(lp), 16, 0, 0)

// ---------------------------------------------------------------------------
// One fused convert kernel: x->x16, W_in->win16, W_out->wout16,
// W_ssm->wssm16 zero-padded from 96 to 128 rows (GLL-safe for GEMM2).
// ---------------------------------------------------------------------------
__global__ __launch_bounds__(256)
void cvt_all(const float* __restrict__ x, const float* __restrict__ w_in,
             const float* __restrict__ w_out, const float* __restrict__ w_ssm,
             _Float16* __restrict__ x16, _Float16* __restrict__ win16,
             _Float16* __restrict__ wout16, _Float16* __restrict__ wssm16)
{
    const int idx = blockIdx.x * 256 + threadIdx.x;
    const int R1 = MROWS * DMODEL / 4;            // x
    const int R2 = R1 + 2 * INNER * DMODEL / 4;   // W_in
    const int R3 = R2 + DMODEL * INNER / 4;       // W_out
    const int R4 = R3 + 128 * INNER / 4;          // W_ssm (padded)
    const float* src; _Float16* dst; int i;
    if (idx < R1)      { src = x;     dst = x16;    i = idx; }
    else if (idx < R2) { src = w_in;  dst = win16;  i = idx - R1; }
    else if (idx < R3) { src = w_out; dst = wout16; i = idx - R2; }
    else if (idx < R4) {
        i = idx - R3;                               // over 128x2048/4
        const int row = i / (INNER / 4);
        half4 h = (half4){0, 0, 0, 0};
        if (row < 96) {
            const float4 v = ((const float4*)w_ssm)[i];
            h.x = (_Float16)v.x; h.y = (_Float16)v.y;
            h.z = (_Float16)v.z; h.w = (_Float16)v.w;
        }
        *(half4*)(wssm16 + (size_t)i * 4) = h;
        return;
    } else return;
    const float4 v = ((const float4*)src)[i];
    half4 h;
    h.x = (_Float16)v.x; h.y = (_Float16)v.y;
    h.z = (_Float16)v.z; h.w = (_Float16)v.w;
    *(half4*)(dst + (size_t)i * 4) = h;
}

// ---------------------------------------------------------------------------
// fp16 MFMA NT-GEMM, double-buffered LDS, ONE barrier per K-iteration.
// 128x128 tile, 4 waves x 4x4 tiles of mfma_f32_16x16x32_f16, BK=32.
// EPI 1: cols < INNER -> fp32 C (ld INNER); cols >= INNER -> fp16 Cg (ld INNER)
// EPI 2: atomicAdd into fp32 C (ld ldcN), col < ldcN... (N guard = ldcN)
// ---------------------------------------------------------------------------
template<int EPI>
__global__ __launch_bounds__(256)
void gemm_f16(const _Float16* __restrict__ A, int lda,
              const _Float16* __restrict__ B, int ldb,
              float* __restrict__ C, _Float16* __restrict__ Cg,
              int ldc, int N, int kchunk)
{
    __shared__ __align__(16) _Float16 sA[2][4 * 128 * 8];  // 8 KB each
    __shared__ __align__(16) _Float16 sB[2][4 * 128 * 8];

    const int tid  = threadIdx.x;
    const int w    = tid >> 6;        // wave 0..3 (owns k-group w)
    const int lane = tid & 63;
    const int ln15 = lane & 15;
    const int q    = lane >> 4;       // k-quad 0..3
    const int wm   = w & 1, wn = w >> 1;
    const int m0 = blockIdx.x * 128, n0 = blockIdx.y * 128;
    const int kbeg = blockIdx.z * kchunk;

    floatx4 acc[4][4];
    #pragma unroll
    for (int i = 0; i < 4; ++i)
        #pragma unroll
        for (int j = 0; j < 4; ++j)
            acc[i][j] = (floatx4){0.f, 0.f, 0.f, 0.f};

    const size_t a0 = (size_t)(m0 + lane) * lda + kbeg;
    const size_t a1 = (size_t)(m0 + 64 + lane) * lda + kbeg;
    const size_t b0 = (size_t)(n0 + lane) * ldb + kbeg;
    const size_t b1 = (size_t)(n0 + 64 + lane) * ldb + kbeg;
    const int wo0 = (w * 128 + 0) * 8, wo1 = (w * 128 + 64) * 8;

    // prologue prefetch into buffer 0
    {
        const int kg = w * 8;
        GLL(A + a0 + kg, &sA[0][wo0]);
        GLL(A + a1 + kg, &sA[0][wo1]);
        GLL(B + b0 + kg, &sB[0][wo0]);
        GLL(B + b1 + kg, &sB[0][wo1]);
    }

    const int niter = kchunk >> 5;
    for (int i = 0; i < niter; ++i) {
        __syncthreads();   // drains buf[i&1]'s loads (issued one full compute ago)
        if (i + 1 < niter) {
            const int kg = (i + 1) * 32 + w * 8;
            const int nb = (i + 1) & 1;
            GLL(A + a0 + kg, &sA[nb][wo0]);
            GLL(A + a1 + kg, &sA[nb][wo1]);
            GLL(B + b0 + kg, &sB[nb][wo0]);
            GLL(B + b1 + kg, &sB[nb][wo1]);
        }
        const _Float16* bufA = sA[i & 1];
        const _Float16* bufB = sB[i & 1];
        half8 fa[4], fb[4];
        #pragma unroll
        for (int t = 0; t < 4; ++t) {
            fa[t] = *(const half8*)&bufA[(q * 128 + wm * 64 + t * 16 + ln15) * 8];
            fb[t] = *(const half8*)&bufB[(q * 128 + wn * 64 + t * 16 + ln15) * 8];
        }
        #pragma unroll
        for (int mt = 0; mt < 4; ++mt)
            #pragma unroll
            for (int nt = 0; nt < 4; ++nt)
                acc[mt][nt] = __builtin_amdgcn_mfma_f32_16x16x32_f16(
                    fa[mt], fb[nt], acc[mt][nt], 0, 0, 0);
    }

    // epilogue: C/D layout col=lane&15, row=q*4+reg
    #pragma unroll
    for (int mt = 0; mt < 4; ++mt) {
        const int rowb = m0 + wm * 64 + mt * 16 + q * 4;
        #pragma unroll
        for (int nt = 0; nt < 4; ++nt) {
            const int col = n0 + wn * 64 + nt * 16 + ln15;
            #pragma unroll
            for (int r = 0; r < 4; ++r) {
                const float v = acc[mt][nt][r];
                const size_t row = (size_t)(rowb + r);
                if (EPI == 1) {
                    if (n0 < INNER) C[row * INNER + col] = v;
                    else Cg[row * INNER + (col - INNER)] = (_Float16)v;
                } else {                      // EPI 2: split-K atomic, col<N
                    if (col < N) atomicAdd(&C[row * ldc + col], v);
                }
            }
        }
    }
}

// ---------------------------------------------------------------------------
// fp32 NT-GEMM, MODE 1: softplus(c + bias[col]) — used for the dt GEMM only.
// ---------------------------------------------------------------------------
__global__ __launch_bounds__(256)
void gemm_nt_sp(const float* __restrict__ A, int lda,
                const float* __restrict__ Bm, int ldb,
                float* __restrict__ C, int ldc,
                int N, int K, const float* __restrict__ bias)
{
    __shared__ float As[16][68];
    __shared__ float Bs[16][68];
    const int m0 = blockIdx.x * 64;
    const int n0 = blockIdx.y * 64;
    const int tid = threadIdx.x;
    const int tm = tid >> 4;
    const int tn = tid & 15;
    const int lrow = tid >> 2;
    const int lk   = (tid & 3) << 2;

    float acc[4][4] = {{0.f}};

    for (int k0 = 0; k0 < K; k0 += 16) {
        float4 a4 = *(const float4*)(A + (size_t)(m0 + lrow) * lda + (k0 + lk));
        float4 b4 = *(const float4*)(Bm + (size_t)(n0 + lrow) * ldb + (k0 + lk));
        As[lk+0][lrow] = a4.x; As[lk+1][lrow] = a4.y;
        As[lk+2][lrow] = a4.z; As[lk+3][lrow] = a4.w;
        Bs[lk+0][lrow] = b4.x; Bs[lk+1][lrow] = b4.y;
        Bs[lk+2][lrow] = b4.z; Bs[lk+3][lrow] = b4.w;
        __syncthreads();
        #pragma unroll
        for (int kk = 0; kk < 16; ++kk) {
            float4 av = *(const float4*)&As[kk][tm << 2];
            float4 bv = *(const float4*)&Bs[kk][tn << 2];
            float am[4] = {av.x, av.y, av.z, av.w};
            float bn[4] = {bv.x, bv.y, bv.z, bv.w};
            #pragma unroll
            for (int i = 0; i < 4; ++i)
                #pragma unroll
                for (int j = 0; j < 4; ++j)
                    acc[i][j] = fmaf(am[i], bn[j], acc[i][j]);
        }
        __syncthreads();
    }

    #pragma unroll
    for (int i = 0; i < 4; ++i) {
        const int row = m0 + (tm << 2) + i;
        #pragma unroll
        for (int j = 0; j < 4; ++j) {
            const int col = n0 + (tn << 2) + j;
            float v = acc[i][j] + bias[col];
            v = (v > 20.f) ? v : log1pf(__expf(v));
            C[(size_t)row * ldc + col] = v;
        }
    }
}

// ---------------------------------------------------------------------------
// Depthwise causal conv (k=4) on dense u32 [M, INNER], then SiLU.
// Emits u_act (fp32, for scan) and u16 (fp16, for GEMM2). 4 channels/thread.
// ---------------------------------------------------------------------------
__global__ __launch_bounds__(256)
void conv_silu(const float* __restrict__ u32,
               const float* __restrict__ conv_w,
               float* __restrict__ u_act, _Float16* __restrict__ u16)
{
    const int idx = blockIdx.x * 256 + threadIdx.x;  // over M*INNER/4
    const int c4 = idx & (INNER / 4 - 1);
    const int t  = (idx >> 9) & (LL - 1);
    const int bb = idx >> 20;
    const int d0 = c4 * 4;
    const size_t base = (size_t)bb * LL;

    const float4 w0 = *(const float4*)(conv_w + (d0 + 0) * KCONV);
    const float4 w1 = *(const float4*)(conv_w + (d0 + 1) * KCONV);
    const float4 w2 = *(const float4*)(conv_w + (d0 + 2) * KCONV);
    const float4 w3 = *(const float4*)(conv_w + (d0 + 3) * KCONV);
    const float wj[4][4] = {{w0.x,w0.y,w0.z,w0.w}, {w1.x,w1.y,w1.z,w1.w},
                            {w2.x,w2.y,w2.z,w2.w}, {w3.x,w3.y,w3.z,w3.w}};
    float s[4] = {0.f, 0.f, 0.f, 0.f};
    #pragma unroll
    for (int j = 0; j < KCONV; ++j) {
        const int ts = t + j - (KCONV - 1);
        if (ts >= 0) {
            const float4 v = *(const float4*)(u32 + (base + ts) * INNER + d0);
            s[0] = fmaf(v.x, wj[0][j], s[0]);
            s[1] = fmaf(v.y, wj[1][j], s[1]);
            s[2] = fmaf(v.z, wj[2][j], s[2]);
            s[3] = fmaf(v.w, wj[3][j], s[3]);
        }
    }
    float4 o; half4 o16;
    o.x = s[0] / (1.f + __expf(-s[0])); o16.x = (_Float16)o.x;
    o.y = s[1] / (1.f + __expf(-s[1])); o16.y = (_Float16)o.y;
    o.z = s[2] / (1.f + __expf(-s[2])); o16.z = (_Float16)o.z;
    o.w = s[3] / (1.f + __expf(-s[3])); o16.w = (_Float16)o.w;
    const size_t off = (base + t) * INNER + d0;
    *(float4*)(u_act + off) = o;
    *(half4*)(u16 + off) = o16;
}

// ---------------------------------------------------------------------------
// Scan pass 1: per-chunk summaries (h[16] in registers per thread-channel).
// ---------------------------------------------------------------------------
__global__ __launch_bounds__(256)
void scan_pass1(const float* __restrict__ u_act,
                const float* __restrict__ dtb,
                const float* __restrict__ params,
                const float* __restrict__ log_A,
                float* __restrict__ Hout,
                float* __restrict__ sumdt_out)
{
    const int bid = blockIdx.x;
    const int c   = bid & (SCH - 1);
    const int cg  = (bid >> 6) & 7;
    const int b   = bid >> 9;
    const int tid = threadIdx.x;
    const int d   = cg * 256 + tid;
    const size_t rowbase = (size_t)b * LL + (size_t)c * TCH;

    float A[NST];
    #pragma unroll
    for (int n = 0; n < NST; n += 4) {
        float4 v = *(const float4*)(log_A + (size_t)d * NST + n);
        A[n+0] = -__expf(v.x); A[n+1] = -__expf(v.y);
        A[n+2] = -__expf(v.z); A[n+3] = -__expf(v.w);
    }

    __shared__ float Bs[TCH * NST];
    for (int i = tid; i < TCH * NST; i += 256) {
        const int t = i >> 4, j = i & 15;
        Bs[i] = params[(rowbase + t) * 96 + DRANK + j];
    }
    __syncthreads();

    float h[NST];
    #pragma unroll
    for (int n = 0; n < NST; ++n) h[n] = 0.f;
    float sdt = 0.f;

    #pragma unroll 4
    for (int t = 0; t < TCH; ++t) {
        const float dtv = dtb[(rowbase + t) * INNER + d];
        const float uv  = u_act[(rowbase + t) * INNER + d];
        const float du = dtv * uv;
        sdt += dtv;
        const float4* Bp = (const float4*)&Bs[t * NST];
        const float4 B0 = Bp[0], B1 = Bp[1], B2 = Bp[2], B3 = Bp[3];
        const float Bv[NST] = {B0.x,B0.y,B0.z,B0.w, B1.x,B1.y,B1.z,B1.w,
                               B2.x,B2.y,B2.z,B2.w, B3.x,B3.y,B3.z,B3.w};
        #pragma unroll
        for (int n = 0; n < NST; ++n)
            h[n] = fmaf(__expf(dtv * A[n]), h[n], du * Bv[n]);
    }

    const size_t o = ((size_t)(b * SCH + c) * INNER + d) * NST;
    #pragma unroll
    for (int n = 0; n < NST; n += 4)
        *(float4*)(Hout + o + n) = make_float4(h[n], h[n+1], h[n+2], h[n+3]);
    sumdt_out[(size_t)(b * SCH + c) * INNER + d] = sdt;
}

// ---------------------------------------------------------------------------
// Scan pass 2: serial combine over chunks. One thread = one (b,d,n).
// ---------------------------------------------------------------------------
__global__ __launch_bounds__(256)
void scan_pass2(const float* __restrict__ Hbuf,
                const float* __restrict__ sumdt,
                const float* __restrict__ log_A,
                float* __restrict__ hinit)
{
    const int idx = blockIdx.x * 256 + threadIdx.x;
    const int n = idx & 15;
    const int d = (idx >> 4) & (INNER - 1);
    const int b = idx >> 15;
    const float An = -__expf(log_A[(size_t)d * NST + n]);
    float h = 0.f;
    for (int c = 0; c < SCH; ++c) {
        const size_t o = ((size_t)(b * SCH + c) * INNER + d) * NST + n;
        hinit[o] = h;
        const float P = __expf(An * sumdt[(size_t)(b * SCH + c) * INNER + d]);
        h = Hbuf[o] + P * h;
    }
}

// ---------------------------------------------------------------------------
// Scan pass 3: re-scan each chunk from h_init, fused epilogue:
// yg = (y + u*D) * silu(gate) -> fp16 (feeds GEMM3). gate read as fp16.
// ---------------------------------------------------------------------------
__global__ __launch_bounds__(256)
void scan_pass3(const float* __restrict__ u_act,
                const float* __restrict__ dtb,
                const float* __restrict__ params,
                const _Float16* __restrict__ gate16,  // [M, INNER]
                const float* __restrict__ log_A,
                const float* __restrict__ Dv,
                const float* __restrict__ hinit,
                _Float16* __restrict__ yg16)          // [M, INNER]
{
    const int bid = blockIdx.x;
    const int c   = bid & (SCH - 1);
    const int cg  = (bid >> 6) & 7;
    const int b   = bid >> 9;
    const int tid = threadIdx.x;
    const int d   = cg * 256 + tid;
    const size_t rowbase = (size_t)b * LL + (size_t)c * TCH;

    float A[NST];
    #pragma unroll
    for (int n = 0; n < NST; n += 4) {
        float4 v = *(const float4*)(log_A + (size_t)d * NST + n);
        A[n+0] = -__expf(v.x); A[n+1] = -__expf(v.y);
        A[n+2] = -__expf(v.z); A[n+3] = -__expf(v.w);
    }
    const float Dd = Dv[d];

    __shared__ float BCs[TCH * 32];
    for (int i = tid; i < TCH * 32; i += 256) {
        const int t = i >> 5, j = i & 31;
        BCs[i] = params[(rowbase + t) * 96 + DRANK + j];
    }

    float h[NST];
    {
        const size_t o = ((size_t)(b * SCH + c) * INNER + d) * NST;
        #pragma unroll
        for (int n = 0; n < NST; n += 4) {
            float4 v = *(const float4*)(hinit + o + n);
            h[n] = v.x; h[n+1] = v.y; h[n+2] = v.z; h[n+3] = v.w;
        }
    }
    __syncthreads();

    #pragma unroll 2
    for (int t = 0; t < TCH; ++t) {
        const float dtv = dtb[(rowbase + t) * INNER + d];
        const float uv  = u_act[(rowbase + t) * INNER + d];
        const float gv  = (float)gate16[(rowbase + t) * INNER + d];
        const float du = dtv * uv;
        const float4* Bp = (const float4*)&BCs[t * 32];
        const float4 B0 = Bp[0], B1 = Bp[1], B2 = Bp[2], B3 = Bp[3];
        const float4 C0 = Bp[4], C1 = Bp[5], C2 = Bp[6], C3 = Bp[7];
        const float Bv[NST] = {B0.x,B0.y,B0.z,B0.w, B1.x,B1.y,B1.z,B1.w,
                               B2.x,B2.y,B2.z,B2.w, B3.x,B3.y,B3.z,B3.w};
        const float Cv[NST] = {C0.x,C0.y,C0.z,C0.w, C1.x,C1.y,C1.z,C1.w,
                               C2.x,C2.y,C2.z,C2.w, C3.x,C3.y,C3.z,C3.w};
        #pragma unroll
        for (int n = 0; n < NST; ++n)
            h[n] = fmaf(__expf(dtv * A[n]), h[n], du * Bv[n]);
        float p[8];
        #pragma unroll
        for (int n = 0; n < 8; ++n)
            p[n] = fmaf(h[n], Cv[n], h[n+8] * Cv[n+8]);
        const float y = ((p[0]+p[1]) + (p[2]+p[3])) + ((p[4]+p[5]) + (p[6]+p[7]));
        const float sg = gv / (1.f + __expf(-gv));
        yg16[(rowbase + t) * INNER + d] = (_Float16)((y + uv * Dd) * sg);
    }
}

// ---------------------------------------------------------------------------
extern "C" void kernel_launch(void* const* d_in, const int* in_sizes, int n_in,
                              void* d_out, int out_size, void* d_ws, size_t ws_size,
                              hipStream_t stream)
{
    const float* x     = (const float*)d_in[0];
    const float* W_in  = (const float*)d_in[1];
    const float* convw = (const float*)d_in[2];
    const float* W_ssm = (const float*)d_in[3];
    const float* W_dt  = (const float*)d_in[4];
    const float* b_dt  = (const float*)d_in[5];
    const float* log_A = (const float*)d_in[6];
    const float* Dv    = (const float*)d_in[7];
    const float* W_out = (const float*)d_in[8];
    float* out = (float*)d_out;

    float* ws = (float*)d_ws;
    float* u32    = ws;                                       // 8.4M floats
    float* u_act  = u32    + (size_t)MROWS * INNER;           // 8.4M
    float* dt_buf = u_act  + (size_t)MROWS * INNER;           // 8.4M
    float* params = dt_buf + (size_t)MROWS * INNER;           // 393216
    float* Hbuf   = params + (size_t)MROWS * 96;              // 4.2M
    float* hinit  = Hbuf   + (size_t)BB * SCH * INNER * NST;  // 4.2M
    float* sumdt  = hinit  + (size_t)BB * SCH * INNER * NST;  // 262144
    _Float16* x16    = (_Float16*)(sumdt + (size_t)BB * SCH * INNER);
    _Float16* win16  = x16    + (size_t)MROWS * DMODEL;
    _Float16* wout16 = win16  + (size_t)(2 * INNER) * DMODEL;
    _Float16* wssm16 = wout16 + (size_t)DMODEL * INNER;       // 128 x 2048 (padded)
    _Float16* gate16 = wssm16 + (size_t)128 * INNER;
    _Float16* u16    = gate16 + (size_t)MROWS * INNER;
    _Float16* yg16   = u16    + (size_t)MROWS * INNER;

    // zero accumulators for split-K atomics
    hipMemsetAsync(params, 0, (size_t)MROWS * 96 * sizeof(float), stream);
    hipMemsetAsync(out, 0, (size_t)MROWS * DMODEL * sizeof(float), stream);

    // 0. all fp32->fp16 converts (+ W_ssm zero-pad to 128 rows)
    {
        const int total4 = MROWS * DMODEL / 4 + 2 * INNER * DMODEL / 4 +
                           DMODEL * INNER / 4 + 128 * INNER / 4;
        cvt_all<<<(total4 + 255) / 256, 256, 0, stream>>>(
            x, W_in, W_out, W_ssm, x16, win16, wout16, wssm16);
    }

    // 1. xz = x @ W_in.T -> u32 (fp32) | gate16 (fp16)   M=4096 N=4096 K=1024
    gemm_f16<1><<<dim3(32, 32, 1), 256, 0, stream>>>(
        x16, DMODEL, win16, DMODEL, u32, gate16, INNER, 2 * INNER, DMODEL);

    // 2. u_act(+u16) = silu(causal_conv(u32))
    conv_silu<<<(MROWS * INNER / 4) / 256, 256, 0, stream>>>(
        u32, convw, u_act, u16);

    // 3. params = u16 @ wssm16.T  (fp16 MFMA, split-K x8, atomic)  N=96
    gemm_f16<2><<<dim3(32, 1, 8), 256, 0, stream>>>(
        u16, INNER, wssm16, INNER, params, nullptr, 96, 96, INNER / 8);

    // 4. dt = softplus(d_low @ W_dt.T + b_dt)  M=4096 N=2048 K=64 (lda=96)
    gemm_nt_sp<<<dim3(64, 32), 256, 0, stream>>>(
        params, 96, W_dt, DRANK, dt_buf, INNER, INNER, DRANK, b_dt);

    // 5. chunked selective scan (3 passes); pass3 emits fp16 yg
    scan_pass1<<<BB * (INNER / 256) * SCH, 256, 0, stream>>>(
        u_act, dt_buf, params, log_A, Hbuf, sumdt);
    scan_pass2<<<BB * INNER * NST / 256, 256, 0, stream>>>(
        Hbuf, sumdt, log_A, hinit);
    scan_pass3<<<BB * (INNER / 256) * SCH, 256, 0, stream>>>(
        u_act, dt_buf, params, gate16, log_A, Dv, hinit, yg16);

    // 6. out = yg @ W_out.T  (fp16 MFMA, split-K x2, atomic)  N=1024
    gemm_f16<2><<<dim3(32, 8, 2), 256, 0, stream>>>(
        yg16, INNER, wout16, INNER, out, nullptr, DMODEL, DMODEL, INNER / 2);
}